// Round 1
// baseline (1995.342 us; speedup 1.0000x reference)
//
#include <hip/hip_runtime.h>
#include <math.h>

#define NROWS 262144
#define DDIM  1024
#define EEXP  64
#define NDOCS 1024

// ws layout (floats): sum_w [NDOCS*EEXP] | sum_w2 [NDOCS*EEXP] | counts [NDOCS]
#define WS_FLOATS (NDOCS*EEXP*2 + NDOCS)

__global__ __launch_bounds__(256) void zero_ws_kernel(float* ws) {
    int i = blockIdx.x * 256 + threadIdx.x;
    if (i < WS_FLOATS) ws[i] = 0.0f;
}

// Fused: GEMM (64x64 tile over K=1024) -> softmax -> w write + atomic segment sums
__global__ __launch_bounds__(256) void gemm_softmax_kernel(
    const float* __restrict__ x,
    const int*   __restrict__ doc_idx,
    const float* __restrict__ Wg,
    float*       __restrict__ w_out,
    float*       __restrict__ sum_w,
    float*       __restrict__ sum_w2,
    float*       __restrict__ counts)
{
    // tiles: xs[32][68], ws_[32][68]  (k-major, stride 68 to break bank conflicts)
    // logits reuse: ls[64][65]
    __shared__ float smem[2 * 32 * 68];   // 17408 B  (>= 64*65 = 16640 B)
    float* xs  = smem;
    float* wsm = smem + 32 * 68;

    const int t  = threadIdx.x;
    const int br = blockIdx.x * 64;
    const int tr = t >> 4;   // 0..15 -> rows tr*4..tr*4+3
    const int tc = t & 15;   // 0..15 -> cols tc*4..tc*4+3

    float acc[4][4];
    #pragma unroll
    for (int i = 0; i < 4; ++i)
        #pragma unroll
        for (int j = 0; j < 4; ++j) acc[i][j] = 0.0f;

    for (int k0 = 0; k0 < DDIM; k0 += 32) {
        // stage tiles: 64 rows x 32 k each, as float4 (8 float4 per row)
        #pragma unroll
        for (int f = t; f < 512; f += 256) {
            const int row = f >> 3;        // 0..63
            const int kq  = f & 7;         // 0..7
            const float4 vx = *(const float4*)(x  + (size_t)(br + row) * DDIM + k0 + kq * 4);
            const float4 vw = *(const float4*)(Wg + (size_t)row        * DDIM + k0 + kq * 4);
            const int kk = kq * 4;
            xs [(kk + 0) * 68 + row] = vx.x;
            xs [(kk + 1) * 68 + row] = vx.y;
            xs [(kk + 2) * 68 + row] = vx.z;
            xs [(kk + 3) * 68 + row] = vx.w;
            wsm[(kk + 0) * 68 + row] = vw.x;
            wsm[(kk + 1) * 68 + row] = vw.y;
            wsm[(kk + 2) * 68 + row] = vw.z;
            wsm[(kk + 3) * 68 + row] = vw.w;
        }
        __syncthreads();

        #pragma unroll
        for (int k = 0; k < 32; ++k) {
            const float4 a = *(const float4*)&xs [k * 68 + tr * 4];
            const float4 b = *(const float4*)&wsm[k * 68 + tc * 4];
            acc[0][0] += a.x * b.x; acc[0][1] += a.x * b.y; acc[0][2] += a.x * b.z; acc[0][3] += a.x * b.w;
            acc[1][0] += a.y * b.x; acc[1][1] += a.y * b.y; acc[1][2] += a.y * b.z; acc[1][3] += a.y * b.w;
            acc[2][0] += a.z * b.x; acc[2][1] += a.z * b.y; acc[2][2] += a.z * b.z; acc[2][3] += a.z * b.w;
            acc[3][0] += a.w * b.x; acc[3][1] += a.w * b.y; acc[3][2] += a.w * b.z; acc[3][3] += a.w * b.w;
        }
        __syncthreads();
    }

    // dump logits to LDS (reuse smem), ls[64][65]
    float* ls = smem;
    #pragma unroll
    for (int i = 0; i < 4; ++i)
        #pragma unroll
        for (int j = 0; j < 4; ++j)
            ls[(tr * 4 + i) * 65 + tc * 4 + j] = acc[i][j];
    __syncthreads();

    // softmax: 4 consecutive lanes per row; each lane owns 16 experts
    const int g  = t >> 2;   // row 0..63
    const int l4 = t & 3;    // 0..3
    float v[16];
    float m = -INFINITY;
    #pragma unroll
    for (int i = 0; i < 16; ++i) {
        v[i] = ls[g * 65 + l4 * 16 + i];
        m = fmaxf(m, v[i]);
    }
    m = fmaxf(m, __shfl_xor(m, 1));
    m = fmaxf(m, __shfl_xor(m, 2));
    float s = 0.0f;
    #pragma unroll
    for (int i = 0; i < 16; ++i) {
        v[i] = __expf(v[i] - m);
        s += v[i];
    }
    s += __shfl_xor(s, 1);
    s += __shfl_xor(s, 2);
    const float inv = 1.0f / s;

    const int row = br + g;
    const int doc = doc_idx[row];
    float* wo  = w_out  + (size_t)row * EEXP + l4 * 16;
    float* sw  = sum_w  + (size_t)doc * EEXP + l4 * 16;
    float* sw2 = sum_w2 + (size_t)doc * EEXP + l4 * 16;

    #pragma unroll
    for (int q = 0; q < 4; ++q) {
        float4 wq;
        wq.x = v[q * 4 + 0] * inv;
        wq.y = v[q * 4 + 1] * inv;
        wq.z = v[q * 4 + 2] * inv;
        wq.w = v[q * 4 + 3] * inv;
        *(float4*)(wo + q * 4) = wq;
        atomicAdd(&sw[q * 4 + 0], wq.x);
        atomicAdd(&sw[q * 4 + 1], wq.y);
        atomicAdd(&sw[q * 4 + 2], wq.z);
        atomicAdd(&sw[q * 4 + 3], wq.w);
        atomicAdd(&sw2[q * 4 + 0], wq.x * wq.x);
        atomicAdd(&sw2[q * 4 + 1], wq.y * wq.y);
        atomicAdd(&sw2[q * 4 + 2], wq.z * wq.z);
        atomicAdd(&sw2[q * 4 + 3], wq.w * wq.w);
    }
    if (l4 == 0) atomicAdd(&counts[doc], 1.0f);
}

__global__ __launch_bounds__(256) void finalize_kernel(
    const float* __restrict__ sum_w,
    const float* __restrict__ sum_w2,
    const float* __restrict__ counts,
    float*       __restrict__ pen_out)
{
    const int t = threadIdx.x;
    float ps = 0.0f, un = 0.0f;
    for (int d = t; d < NDOCS; d += 256) {
        const float n    = counts[d];
        const float safe = fmaxf(n, 1.0f);
        float s2 = 0.0f, s1sq = 0.0f;
        for (int e = 0; e < EEXP; ++e) {
            const float a = sum_w[(size_t)d * EEXP + e];
            const float b = sum_w2[(size_t)d * EEXP + e];
            s2   += b;
            s1sq += a * a;
        }
        const float ssd = s2 - s1sq / safe;
        const float mse = ssd / (safe * (float)EEXP);
        if (n > 1.0f) ps += mse;
        if (n > 0.0f) un += 1.0f;
    }
    // wave reduce (wave64)
    #pragma unroll
    for (int off = 32; off > 0; off >>= 1) {
        ps += __shfl_down(ps, off);
        un += __shfl_down(un, off);
    }
    __shared__ float sps[4], sun[4];
    const int wid = t >> 6;
    if ((t & 63) == 0) { sps[wid] = ps; sun[wid] = un; }
    __syncthreads();
    if (t == 0) {
        float tps = sps[0] + sps[1] + sps[2] + sps[3];
        float tun = sun[0] + sun[1] + sun[2] + sun[3];
        pen_out[0] = tps / tun;
    }
}

extern "C" void kernel_launch(void* const* d_in, const int* in_sizes, int n_in,
                              void* d_out, int out_size, void* d_ws, size_t ws_size,
                              hipStream_t stream) {
    const float* x   = (const float*)d_in[0];
    const int*   idx = (const int*)d_in[1];
    const float* Wg  = (const float*)d_in[2];

    float* out   = (float*)d_out;
    float* w_out = out;                                  // NROWS*EEXP floats
    float* pen   = out + (size_t)NROWS * EEXP;           // 1 float

    float* sw  = (float*)d_ws;
    float* sw2 = sw  + (size_t)NDOCS * EEXP;
    float* cnt = sw2 + (size_t)NDOCS * EEXP;

    zero_ws_kernel<<<(WS_FLOATS + 255) / 256, 256, 0, stream>>>((float*)d_ws);
    gemm_softmax_kernel<<<NROWS / 64, 256, 0, stream>>>(x, idx, Wg, w_out, sw, sw2, cnt);
    finalize_kernel<<<1, 256, 0, stream>>>(sw, sw2, cnt, pen);
}

// Round 2
// 677.441 us; speedup vs baseline: 2.9454x; 2.9454x over previous
//
#include <hip/hip_runtime.h>
#include <math.h>

#define NROWS 262144
#define DDIM  1024
#define EEXP  64
#define NDOCS 1024

// ws layout (ints/floats, 4B each):
//   sorted_rows [NROWS]
//   offsets     [NDOCS+1]
//   cnt         [NDOCS]
//   cursor      [NDOCS]
//   pen_sum (f32), uniq (f32)

__global__ __launch_bounds__(1024) void init_kernel(int* cnt, float* pen_sum, float* uniq) {
    const int t = threadIdx.x;
    cnt[t] = 0;
    if (t == 0) { pen_sum[0] = 0.0f; uniq[0] = 0.0f; }
}

__global__ __launch_bounds__(256) void hist_kernel(const int* __restrict__ idx, int* __restrict__ cnt) {
    const int r = blockIdx.x * 256 + threadIdx.x;
    if (r < NROWS) atomicAdd(&cnt[idx[r]], 1);
}

__global__ __launch_bounds__(1024) void scan_kernel(const int* __restrict__ cnt,
                                                    int* __restrict__ offsets,
                                                    int* __restrict__ cursor) {
    __shared__ int sbuf[NDOCS];
    const int t = threadIdx.x;
    const int my = cnt[t];
    sbuf[t] = my;
    __syncthreads();
    for (int off = 1; off < NDOCS; off <<= 1) {
        int add = (t >= off) ? sbuf[t - off] : 0;
        __syncthreads();
        sbuf[t] += add;
        __syncthreads();
    }
    const int excl = sbuf[t] - my;
    offsets[t] = excl;
    cursor[t]  = excl;
    if (t == NDOCS - 1) offsets[NDOCS] = sbuf[t];
}

__global__ __launch_bounds__(256) void scatter_kernel(const int* __restrict__ idx,
                                                      int* __restrict__ cursor,
                                                      int* __restrict__ sorted_rows) {
    const int r = blockIdx.x * 256 + threadIdx.x;
    if (r < NROWS) {
        const int pos = atomicAdd(&cursor[idx[r]], 1);
        sorted_rows[pos] = r;
    }
}

// Fused GEMM (64x64 tile over K=1024) -> softmax -> w write. No atomics.
__global__ __launch_bounds__(256) void gemm_softmax_kernel(
    const float* __restrict__ x,
    const float* __restrict__ Wg,
    float*       __restrict__ w_out)
{
    __shared__ float smem[2 * 32 * 68];   // 17408 B
    float* xs  = smem;
    float* wsm = smem + 32 * 68;

    const int t  = threadIdx.x;
    const int br = blockIdx.x * 64;
    const int tr = t >> 4;   // 0..15 -> rows tr*4..tr*4+3
    const int tc = t & 15;   // 0..15 -> cols tc*4..tc*4+3

    float acc[4][4];
    #pragma unroll
    for (int i = 0; i < 4; ++i)
        #pragma unroll
        for (int j = 0; j < 4; ++j) acc[i][j] = 0.0f;

    for (int k0 = 0; k0 < DDIM; k0 += 32) {
        #pragma unroll
        for (int f = t; f < 512; f += 256) {
            const int row = f >> 3;        // 0..63
            const int kq  = f & 7;         // 0..7
            const float4 vx = *(const float4*)(x  + (size_t)(br + row) * DDIM + k0 + kq * 4);
            const float4 vw = *(const float4*)(Wg + (size_t)row        * DDIM + k0 + kq * 4);
            const int kk = kq * 4;
            xs [(kk + 0) * 68 + row] = vx.x;
            xs [(kk + 1) * 68 + row] = vx.y;
            xs [(kk + 2) * 68 + row] = vx.z;
            xs [(kk + 3) * 68 + row] = vx.w;
            wsm[(kk + 0) * 68 + row] = vw.x;
            wsm[(kk + 1) * 68 + row] = vw.y;
            wsm[(kk + 2) * 68 + row] = vw.z;
            wsm[(kk + 3) * 68 + row] = vw.w;
        }
        __syncthreads();

        #pragma unroll
        for (int k = 0; k < 32; ++k) {
            const float4 a = *(const float4*)&xs [k * 68 + tr * 4];
            const float4 b = *(const float4*)&wsm[k * 68 + tc * 4];
            acc[0][0] += a.x * b.x; acc[0][1] += a.x * b.y; acc[0][2] += a.x * b.z; acc[0][3] += a.x * b.w;
            acc[1][0] += a.y * b.x; acc[1][1] += a.y * b.y; acc[1][2] += a.y * b.z; acc[1][3] += a.y * b.w;
            acc[2][0] += a.z * b.x; acc[2][1] += a.z * b.y; acc[2][2] += a.z * b.z; acc[2][3] += a.z * b.w;
            acc[3][0] += a.w * b.x; acc[3][1] += a.w * b.y; acc[3][2] += a.w * b.z; acc[3][3] += a.w * b.w;
        }
        __syncthreads();
    }

    // logits to LDS (reuse smem), ls[64][65]
    float* ls = smem;
    #pragma unroll
    for (int i = 0; i < 4; ++i)
        #pragma unroll
        for (int j = 0; j < 4; ++j)
            ls[(tr * 4 + i) * 65 + tc * 4 + j] = acc[i][j];
    __syncthreads();

    // softmax: 4 consecutive lanes per row; each lane owns 16 experts
    const int g  = t >> 2;   // row 0..63
    const int l4 = t & 3;    // 0..3
    float v[16];
    float m = -INFINITY;
    #pragma unroll
    for (int i = 0; i < 16; ++i) {
        v[i] = ls[g * 65 + l4 * 16 + i];
        m = fmaxf(m, v[i]);
    }
    m = fmaxf(m, __shfl_xor(m, 1));
    m = fmaxf(m, __shfl_xor(m, 2));
    float s = 0.0f;
    #pragma unroll
    for (int i = 0; i < 16; ++i) {
        v[i] = __expf(v[i] - m);
        s += v[i];
    }
    s += __shfl_xor(s, 1);
    s += __shfl_xor(s, 2);
    const float inv = 1.0f / s;

    float* wo = w_out + (size_t)(br + g) * EEXP + l4 * 16;
    #pragma unroll
    for (int q = 0; q < 4; ++q) {
        float4 wq;
        wq.x = v[q * 4 + 0] * inv;
        wq.y = v[q * 4 + 1] * inv;
        wq.z = v[q * 4 + 2] * inv;
        wq.w = v[q * 4 + 3] * inv;
        *(float4*)(wo + q * 4) = wq;
    }
}

// One block per doc: sum w and w^2 over the doc's rows, compute ssd/mse, 2 scalar atomics.
__global__ __launch_bounds__(256) void segsum_kernel(
    const float* __restrict__ w,
    const int*   __restrict__ sorted_rows,
    const int*   __restrict__ offsets,
    float*       __restrict__ pen_sum,
    float*       __restrict__ uniq)
{
    const int d  = blockIdx.x;
    const int t  = threadIdx.x;
    const int e  = t & 63;
    const int rg = t >> 6;
    const int start = offsets[d];
    const int end   = offsets[d + 1];
    const int n     = end - start;

    float s1 = 0.0f, s2 = 0.0f;
    for (int i = start + rg; i < end; i += 4) {
        const int row = sorted_rows[i];
        const float v = w[(size_t)row * EEXP + e];
        s1 += v;
        s2 += v * v;
    }

    __shared__ float ls1[4][64], ls2[4][64];
    ls1[rg][e] = s1;
    ls2[rg][e] = s2;
    __syncthreads();

    if (t < 64) {
        const float a = ls1[0][e] + ls1[1][e] + ls1[2][e] + ls1[3][e];
        const float b = ls2[0][e] + ls2[1][e] + ls2[2][e] + ls2[3][e];
        const float safe = fmaxf((float)n, 1.0f);
        float contrib = b - a * a / safe;     // sum_w2 - n*centroid^2 for this expert
        #pragma unroll
        for (int off = 32; off > 0; off >>= 1)
            contrib += __shfl_down(contrib, off);
        if (e == 0) {
            if (n > 1) atomicAdd(pen_sum, contrib / (safe * (float)EEXP));
            if (n > 0) atomicAdd(uniq, 1.0f);
        }
    }
}

__global__ void final_kernel(const float* __restrict__ pen_sum,
                             const float* __restrict__ uniq,
                             float* __restrict__ pen_out) {
    pen_out[0] = pen_sum[0] / uniq[0];
}

extern "C" void kernel_launch(void* const* d_in, const int* in_sizes, int n_in,
                              void* d_out, int out_size, void* d_ws, size_t ws_size,
                              hipStream_t stream) {
    const float* x   = (const float*)d_in[0];
    const int*   idx = (const int*)d_in[1];
    const float* Wg  = (const float*)d_in[2];

    float* out   = (float*)d_out;
    float* w_out = out;                                  // NROWS*EEXP floats
    float* pen   = out + (size_t)NROWS * EEXP;           // 1 float

    int* wsI         = (int*)d_ws;
    int* sorted_rows = wsI;
    int* offsets     = sorted_rows + NROWS;
    int* cnt         = offsets + NDOCS + 1;
    int* cursor      = cnt + NDOCS;
    float* pen_sum   = (float*)(cursor + NDOCS);
    float* uniq      = pen_sum + 1;

    init_kernel<<<1, 1024, 0, stream>>>(cnt, pen_sum, uniq);
    hist_kernel<<<NROWS / 256, 256, 0, stream>>>(idx, cnt);
    scan_kernel<<<1, 1024, 0, stream>>>(cnt, offsets, cursor);
    scatter_kernel<<<NROWS / 256, 256, 0, stream>>>(idx, cursor, sorted_rows);
    gemm_softmax_kernel<<<NROWS / 64, 256, 0, stream>>>(x, Wg, w_out);
    segsum_kernel<<<NDOCS, 256, 0, stream>>>(w_out, sorted_rows, offsets, pen_sum, uniq);
    final_kernel<<<1, 1, 0, stream>>>(pen_sum, uniq, pen);
}

// Round 3
// 481.967 us; speedup vs baseline: 4.1400x; 1.4056x over previous
//
#include <hip/hip_runtime.h>
#include <math.h>

#define NROWS 262144
#define DDIM  1024
#define EEXP  64
#define NDOCS 1024

typedef __attribute__((ext_vector_type(8))) __bf16 bf16x8;
typedef __attribute__((ext_vector_type(4))) float  f32x4;
typedef unsigned short ushort_t;
typedef unsigned int   uint_t;

// ws layout:
//   Whg  ushort[EEXP*DDIM]   (128 KB)  W hi bf16
//   Wlg  ushort[EEXP*DDIM]   (128 KB)  W lo bf16
//   sorted_rows int[NROWS]
//   offsets int[NDOCS+1]
//   cnt     int[NDOCS]
//   cursor  int[NDOCS]
//   pen_sum f32, uniq f32

__global__ __launch_bounds__(1024) void init_kernel(int* cnt, float* pen_sum, float* uniq) {
    const int t = threadIdx.x;
    cnt[t] = 0;
    if (t == 0) { pen_sum[0] = 0.0f; uniq[0] = 0.0f; }
}

__global__ __launch_bounds__(256) void hist_kernel(const int* __restrict__ idx, int* __restrict__ cnt) {
    const int r = blockIdx.x * 256 + threadIdx.x;
    if (r < NROWS) atomicAdd(&cnt[idx[r]], 1);
}

__global__ __launch_bounds__(1024) void scan_kernel(const int* __restrict__ cnt,
                                                    int* __restrict__ offsets,
                                                    int* __restrict__ cursor) {
    __shared__ int sbuf[NDOCS];
    const int t = threadIdx.x;
    const int my = cnt[t];
    sbuf[t] = my;
    __syncthreads();
    for (int off = 1; off < NDOCS; off <<= 1) {
        int add = (t >= off) ? sbuf[t - off] : 0;
        __syncthreads();
        sbuf[t] += add;
        __syncthreads();
    }
    const int excl = sbuf[t] - my;
    offsets[t] = excl;
    cursor[t]  = excl;
    if (t == NDOCS - 1) offsets[NDOCS] = sbuf[t];
}

__global__ __launch_bounds__(256) void scatter_kernel(const int* __restrict__ idx,
                                                      int* __restrict__ cursor,
                                                      int* __restrict__ sorted_rows) {
    const int r = blockIdx.x * 256 + threadIdx.x;
    if (r < NROWS) {
        const int pos = atomicAdd(&cursor[idx[r]], 1);
        sorted_rows[pos] = r;
    }
}

// Pre-convert W (fp32) -> bf16 hi/lo split. 65536 elements.
__global__ __launch_bounds__(256) void convw_kernel(const float* __restrict__ Wg,
                                                    ushort_t* __restrict__ Whg,
                                                    ushort_t* __restrict__ Wlg) {
    const int i = blockIdx.x * 256 + threadIdx.x;
    const float wv = Wg[i];
    const uint_t b = __float_as_uint(wv);
    const uint_t hib = b & 0xFFFF0000u;
    const float lov = wv - __uint_as_float(hib);
    Whg[i] = (ushort_t)(b >> 16);
    Wlg[i] = (ushort_t)(__float_as_uint(lov) >> 16);
}

// MFMA GEMM (split-bf16, 3 products) + in-register softmax. BM=64, BK=32, 4 waves.
__global__ __launch_bounds__(256) void gemm_softmax_kernel(
    const float*    __restrict__ x,
    const ushort_t* __restrict__ Whg,
    const ushort_t* __restrict__ Wlg,
    float*          __restrict__ w_out)
{
    __shared__ float    xs[64 * 32];   // 8 KB, row stride 32 fp32; 16B-unit XOR swizzle (unit ^ (row&7))
    __shared__ ushort_t whs[64 * 40];  // 5 KB, row stride 40 bf16 (80 B)
    __shared__ ushort_t wls[64 * 40];

    const int t  = threadIdx.x;
    const int br = blockIdx.x * 64;
    const int w  = t >> 6;     // wave 0..3 -> rows w*16..w*16+15
    const int l  = t & 63;
    const int cl = l & 15;     // A-row-in-tile / B-col-in-tile / D-col
    const int g  = l >> 4;     // k-group (8 elems each)

    f32x4 acc[4] = {f32x4{0,0,0,0}, f32x4{0,0,0,0}, f32x4{0,0,0,0}, f32x4{0,0,0,0}};

    // staging coords
    const int se  = t >> 2;    // expert 0..63
    const int skq = t & 3;     // 8-bf16 chunk 0..3

    for (int k0 = 0; k0 < DDIM; k0 += 32) {
        // stage x tile: 64 rows x 32 fp32, swizzled
        #pragma unroll
        for (int ff = 0; ff < 2; ++ff) {
            const int f   = t + ff * 256;
            const int row = f >> 3;
            const int kq  = f & 7;
            const float4 v = *(const float4*)(x + (size_t)(br + row) * DDIM + k0 + kq * 4);
            const int unit = kq ^ (row & 7);
            *(float4*)(xs + row * 32 + unit * 4) = v;
        }
        // stage W hi/lo tiles: 64 experts x 32 bf16 each
        {
            const uint4 vh = *(const uint4*)(Whg + se * DDIM + k0 + skq * 8);
            const uint4 vl = *(const uint4*)(Wlg + se * DDIM + k0 + skq * 8);
            *(uint4*)(whs + se * 40 + skq * 8) = vh;
            *(uint4*)(wls + se * 40 + skq * 8) = vl;
        }
        __syncthreads();

        // A fragment: row = w*16 + cl, k = g*8..g*8+7  (8 fp32, swizzled units)
        const int arow = w * 16 + cl;
        const int u0 = (2 * g + 0) ^ (arow & 7);
        const int u1 = (2 * g + 1) ^ (arow & 7);
        const float4 a0 = *(const float4*)(xs + arow * 32 + u0 * 4);
        const float4 a1 = *(const float4*)(xs + arow * 32 + u1 * 4);

        // split fp32x8 -> bf16x8 hi + bf16x8 lo (packed pairs)
        union { uint_t u[4]; bf16x8 v; } ah, al;
        const float av0[8] = {a0.x, a0.y, a0.z, a0.w, a1.x, a1.y, a1.z, a1.w};
        #pragma unroll
        for (int p = 0; p < 4; ++p) {
            const uint_t b0 = __float_as_uint(av0[2 * p]);
            const uint_t b1 = __float_as_uint(av0[2 * p + 1]);
            ah.u[p] = (b0 >> 16) | (b1 & 0xFFFF0000u);
            const float l0 = av0[2 * p]     - __uint_as_float(b0 & 0xFFFF0000u);
            const float l1 = av0[2 * p + 1] - __uint_as_float(b1 & 0xFFFF0000u);
            al.u[p] = (__float_as_uint(l0) >> 16) | (__float_as_uint(l1) & 0xFFFF0000u);
        }

        #pragma unroll
        for (int c = 0; c < 4; ++c) {
            const int e = c * 16 + cl;
            const bf16x8 bh = *(const bf16x8*)(whs + e * 40 + g * 8);
            const bf16x8 bl = *(const bf16x8*)(wls + e * 40 + g * 8);
            acc[c] = __builtin_amdgcn_mfma_f32_16x16x32_bf16(ah.v, bh, acc[c], 0, 0, 0);
            acc[c] = __builtin_amdgcn_mfma_f32_16x16x32_bf16(ah.v, bl, acc[c], 0, 0, 0);
            acc[c] = __builtin_amdgcn_mfma_f32_16x16x32_bf16(al.v, bh, acc[c], 0, 0, 0);
        }
        __syncthreads();
    }

    // In-register softmax. D mapping: row = g*4 + r, col = c*16 + cl.
    // Row lives in the 16-lane group sharing g -> shfl_xor 1,2,4,8.
    #pragma unroll
    for (int r = 0; r < 4; ++r) {
        const float v0 = acc[0][r], v1 = acc[1][r], v2 = acc[2][r], v3 = acc[3][r];
        float m = fmaxf(fmaxf(v0, v1), fmaxf(v2, v3));
        m = fmaxf(m, __shfl_xor(m, 1));
        m = fmaxf(m, __shfl_xor(m, 2));
        m = fmaxf(m, __shfl_xor(m, 4));
        m = fmaxf(m, __shfl_xor(m, 8));
        const float e0 = __expf(v0 - m);
        const float e1 = __expf(v1 - m);
        const float e2 = __expf(v2 - m);
        const float e3 = __expf(v3 - m);
        float s = e0 + e1 + e2 + e3;
        s += __shfl_xor(s, 1);
        s += __shfl_xor(s, 2);
        s += __shfl_xor(s, 4);
        s += __shfl_xor(s, 8);
        const float inv = 1.0f / s;
        const size_t rowoff = (size_t)(br + w * 16 + g * 4 + r) * EEXP;
        w_out[rowoff +  0 + cl] = e0 * inv;
        w_out[rowoff + 16 + cl] = e1 * inv;
        w_out[rowoff + 32 + cl] = e2 * inv;
        w_out[rowoff + 48 + cl] = e3 * inv;
    }
}

// One block per doc: sum w, w^2 over the doc's rows; 2 scalar atomics per doc.
__global__ __launch_bounds__(256) void segsum_kernel(
    const float* __restrict__ w,
    const int*   __restrict__ sorted_rows,
    const int*   __restrict__ offsets,
    float*       __restrict__ pen_sum,
    float*       __restrict__ uniq)
{
    const int d  = blockIdx.x;
    const int t  = threadIdx.x;
    const int e  = t & 63;
    const int rg = t >> 6;
    const int start = offsets[d];
    const int end   = offsets[d + 1];
    const int n     = end - start;

    float s1 = 0.0f, s2 = 0.0f;
    for (int i = start + rg; i < end; i += 4) {
        const int row = sorted_rows[i];
        const float v = w[(size_t)row * EEXP + e];
        s1 += v;
        s2 += v * v;
    }

    __shared__ float ls1[4][64], ls2[4][64];
    ls1[rg][e] = s1;
    ls2[rg][e] = s2;
    __syncthreads();

    if (t < 64) {
        const float a = ls1[0][e] + ls1[1][e] + ls1[2][e] + ls1[3][e];
        const float b = ls2[0][e] + ls2[1][e] + ls2[2][e] + ls2[3][e];
        const float safe = fmaxf((float)n, 1.0f);
        float contrib = b - a * a / safe;
        #pragma unroll
        for (int off = 32; off > 0; off >>= 1)
            contrib += __shfl_down(contrib, off);
        if (e == 0) {
            if (n > 1) atomicAdd(pen_sum, contrib / (safe * (float)EEXP));
            if (n > 0) atomicAdd(uniq, 1.0f);
        }
    }
}

__global__ void final_kernel(const float* __restrict__ pen_sum,
                             const float* __restrict__ uniq,
                             float* __restrict__ pen_out) {
    pen_out[0] = pen_sum[0] / uniq[0];
}

extern "C" void kernel_launch(void* const* d_in, const int* in_sizes, int n_in,
                              void* d_out, int out_size, void* d_ws, size_t ws_size,
                              hipStream_t stream) {
    const float* x   = (const float*)d_in[0];
    const int*   idx = (const int*)d_in[1];
    const float* Wg  = (const float*)d_in[2];

    float* out   = (float*)d_out;
    float* w_out = out;                                  // NROWS*EEXP floats
    float* pen   = out + (size_t)NROWS * EEXP;           // 1 float

    ushort_t* Whg = (ushort_t*)d_ws;
    ushort_t* Wlg = Whg + (size_t)EEXP * DDIM;
    int* sorted_rows = (int*)(Wlg + (size_t)EEXP * DDIM);
    int* offsets     = sorted_rows + NROWS;
    int* cnt         = offsets + NDOCS + 1;
    int* cursor      = cnt + NDOCS;
    float* pen_sum   = (float*)(cursor + NDOCS);
    float* uniq      = pen_sum + 1;

    init_kernel<<<1, 1024, 0, stream>>>(cnt, pen_sum, uniq);
    hist_kernel<<<NROWS / 256, 256, 0, stream>>>(idx, cnt);
    scan_kernel<<<1, 1024, 0, stream>>>(cnt, offsets, cursor);
    scatter_kernel<<<NROWS / 256, 256, 0, stream>>>(idx, cursor, sorted_rows);
    convw_kernel<<<(EEXP * DDIM) / 256, 256, 0, stream>>>(Wg, Whg, Wlg);
    gemm_softmax_kernel<<<NROWS / 64, 256, 0, stream>>>(x, Whg, Wlg, w_out);
    segsum_kernel<<<NDOCS, 256, 0, stream>>>(w_out, sorted_rows, offsets, pen_sum, uniq);
    final_kernel<<<1, 1, 0, stream>>>(pen_sum, uniq, pen);
}

// Round 4
// 469.246 us; speedup vs baseline: 4.2522x; 1.0271x over previous
//
#include <hip/hip_runtime.h>
#include <math.h>

#define NROWS 262144
#define DDIM  1024
#define EEXP  64
#define NDOCS 1024
#define BM    128
#define BK    32

typedef __attribute__((ext_vector_type(8)))  __bf16 bf16x8;
typedef __attribute__((ext_vector_type(16))) float  f32x16;
typedef unsigned short ushort_t;
typedef unsigned int   uint_t;

// ws layout:
//   Whg ushort[EEXP*DDIM], Wlg ushort[EEXP*DDIM]
//   sorted_rows int[NROWS], offsets int[NDOCS+1], cnt int[NDOCS], cursor int[NDOCS]
//   pen_sum f32, uniq f32

__global__ __launch_bounds__(1024) void init_kernel(int* cnt, float* pen_sum, float* uniq) {
    const int t = threadIdx.x;
    cnt[t] = 0;
    if (t == 0) { pen_sum[0] = 0.0f; uniq[0] = 0.0f; }
}

__global__ __launch_bounds__(256) void hist_kernel(const int* __restrict__ idx, int* __restrict__ cnt) {
    const int r = blockIdx.x * 256 + threadIdx.x;
    if (r < NROWS) atomicAdd(&cnt[idx[r]], 1);
}

__global__ __launch_bounds__(1024) void scan_kernel(const int* __restrict__ cnt,
                                                    int* __restrict__ offsets,
                                                    int* __restrict__ cursor) {
    __shared__ int sbuf[NDOCS];
    const int t = threadIdx.x;
    const int my = cnt[t];
    sbuf[t] = my;
    __syncthreads();
    for (int off = 1; off < NDOCS; off <<= 1) {
        int add = (t >= off) ? sbuf[t - off] : 0;
        __syncthreads();
        sbuf[t] += add;
        __syncthreads();
    }
    const int excl = sbuf[t] - my;
    offsets[t] = excl;
    cursor[t]  = excl;
    if (t == NDOCS - 1) offsets[NDOCS] = sbuf[t];
}

__global__ __launch_bounds__(256) void scatter_kernel(const int* __restrict__ idx,
                                                      int* __restrict__ cursor,
                                                      int* __restrict__ sorted_rows) {
    const int r = blockIdx.x * 256 + threadIdx.x;
    if (r < NROWS) {
        const int pos = atomicAdd(&cursor[idx[r]], 1);
        sorted_rows[pos] = r;
    }
}

__global__ __launch_bounds__(256) void convw_kernel(const float* __restrict__ Wg,
                                                    ushort_t* __restrict__ Whg,
                                                    ushort_t* __restrict__ Wlg) {
    const int i = blockIdx.x * 256 + threadIdx.x;
    const float wv = Wg[i];
    const uint_t b = __float_as_uint(wv);
    const float lov = wv - __uint_as_float(b & 0xFFFF0000u);
    Whg[i] = (ushort_t)(b >> 16);
    Wlg[i] = (ushort_t)(__float_as_uint(lov) >> 16);
}

__device__ __forceinline__ void gl2lds16(const float* g, float* l) {
    __builtin_amdgcn_global_load_lds(
        (const __attribute__((address_space(1))) void*)g,
        (__attribute__((address_space(3))) void*)l,
        16, 0, 0);
}

// MFMA GEMM: BM=128, BK=32, 4 waves, 32x32x16 bf16 split-hi/lo (3 products),
// 2-phase pipeline: stage t+1 (x via global_load_lds pre-swizzled-source; W reg->LDS),
// compute t, one barrier per K-step. In-register softmax epilogue.
__global__ __launch_bounds__(256) void gemm_softmax_kernel(
    const float*    __restrict__ x,
    const ushort_t* __restrict__ Whg,
    const ushort_t* __restrict__ Wlg,
    float*          __restrict__ w_out)
{
    __shared__ float    xs[2][BM * BK];       // 2 x 16 KB, row stride 32 f32 (8 x 16B units), unit ^= row&7
    __shared__ ushort_t whs[2][EEXP * 40];    // 2 x 5 KB, row stride 40 ushort (80 B)
    __shared__ ushort_t wls[2][EEXP * 40];

    const int t   = threadIdx.x;
    const int w   = t >> 6;
    const int l   = t & 63;
    const int cl  = l & 31;     // A-row-in-wave-tile / B-col / D-col
    const int hi  = l >> 5;     // k-half selector
    const size_t br = (size_t)blockIdx.x * BM;

    // x staging lane coords: wave w owns chunks 4w..4w+3; chunk = 8 rows x 8 units
    const int lrow  = l >> 3;   // row within chunk
    const int lunit = l & 7;    // dest 16B unit (linear)

    // W staging coords
    const int se  = t >> 2;     // expert 0..63
    const int skq = t & 3;      // 8-ushort chunk

    f32x16 acc0 = {};
    f32x16 acc1 = {};
    uint4 wh_reg, wl_reg;

    union u8b { uint_t u[4]; bf16x8 v; };

#define STAGE_X(buf, k0) do {                                                          \
        _Pragma("unroll")                                                              \
        for (int i_ = 0; i_ < 4; ++i_) {                                               \
            const int chunk_ = w * 4 + i_;                                             \
            const int row_   = chunk_ * 8 + lrow;                                      \
            const float* gp_ = x + (br + row_) * DDIM + (k0) + ((lunit ^ (row_ & 7)) * 4); \
            gl2lds16(gp_, &xs[buf][chunk_ * 256]);                                     \
        } } while (0)

#define LOAD_W(k0) do {                                                                \
        wh_reg = *(const uint4*)(Whg + (size_t)se * DDIM + (k0) + skq * 8);            \
        wl_reg = *(const uint4*)(Wlg + (size_t)se * DDIM + (k0) + skq * 8);            \
    } while (0)

#define WRITE_W(buf) do {                                                              \
        *(uint4*)(whs[buf] + se * 40 + skq * 8) = wh_reg;                              \
        *(uint4*)(wls[buf] + se * 40 + skq * 8) = wl_reg;                              \
    } while (0)

#define SPLIT8(A, B, AH, AL) do {                                                      \
        const float av_[8] = {A.x, A.y, A.z, A.w, B.x, B.y, B.z, B.w};                 \
        _Pragma("unroll")                                                              \
        for (int p_ = 0; p_ < 4; ++p_) {                                               \
            const uint_t b0_ = __float_as_uint(av_[2 * p_]);                           \
            const uint_t b1_ = __float_as_uint(av_[2 * p_ + 1]);                       \
            AH.u[p_] = (b0_ >> 16) | (b1_ & 0xFFFF0000u);                              \
            const float l0_ = av_[2 * p_]     - __uint_as_float(b0_ & 0xFFFF0000u);    \
            const float l1_ = av_[2 * p_ + 1] - __uint_as_float(b1_ & 0xFFFF0000u);    \
            AL.u[p_] = (__float_as_uint(l0_) >> 16) | (__float_as_uint(l1_) & 0xFFFF0000u); \
        } } while (0)

#define COMPUTE(buf) do {                                                              \
        const int arow_ = w * 32 + cl;                                                 \
        const int sw7_  = arow_ & 7;                                                   \
        const float4 a0_ = *(const float4*)&xs[buf][arow_ * 32 + (((2*hi + 0) ^ sw7_) * 4)]; \
        const float4 a1_ = *(const float4*)&xs[buf][arow_ * 32 + (((2*hi + 1) ^ sw7_) * 4)]; \
        const float4 a2_ = *(const float4*)&xs[buf][arow_ * 32 + (((4 + 2*hi + 0) ^ sw7_) * 4)]; \
        const float4 a3_ = *(const float4*)&xs[buf][arow_ * 32 + (((4 + 2*hi + 1) ^ sw7_) * 4)]; \
        u8b ah0, al0, ah1, al1;                                                        \
        SPLIT8(a0_, a1_, ah0, al0);                                                    \
        SPLIT8(a2_, a3_, ah1, al1);                                                    \
        const int ko_ = 8 * hi;                                                        \
        const bf16x8 bh00 = *(const bf16x8*)(whs[buf] + (cl)      * 40 +      ko_);    \
        const bf16x8 bh01 = *(const bf16x8*)(whs[buf] + (cl)      * 40 + 16 + ko_);    \
        const bf16x8 bh10 = *(const bf16x8*)(whs[buf] + (32 + cl) * 40 +      ko_);    \
        const bf16x8 bh11 = *(const bf16x8*)(whs[buf] + (32 + cl) * 40 + 16 + ko_);    \
        const bf16x8 bl00 = *(const bf16x8*)(wls[buf] + (cl)      * 40 +      ko_);    \
        const bf16x8 bl01 = *(const bf16x8*)(wls[buf] + (cl)      * 40 + 16 + ko_);    \
        const bf16x8 bl10 = *(const bf16x8*)(wls[buf] + (32 + cl) * 40 +      ko_);    \
        const bf16x8 bl11 = *(const bf16x8*)(wls[buf] + (32 + cl) * 40 + 16 + ko_);    \
        acc0 = __builtin_amdgcn_mfma_f32_32x32x16_bf16(ah0.v, bh00, acc0, 0, 0, 0);    \
        acc1 = __builtin_amdgcn_mfma_f32_32x32x16_bf16(ah0.v, bh10, acc1, 0, 0, 0);    \
        acc0 = __builtin_amdgcn_mfma_f32_32x32x16_bf16(ah0.v, bl00, acc0, 0, 0, 0);    \
        acc1 = __builtin_amdgcn_mfma_f32_32x32x16_bf16(ah0.v, bl10, acc1, 0, 0, 0);    \
        acc0 = __builtin_amdgcn_mfma_f32_32x32x16_bf16(al0.v, bh00, acc0, 0, 0, 0);    \
        acc1 = __builtin_amdgcn_mfma_f32_32x32x16_bf16(al0.v, bh10, acc1, 0, 0, 0);    \
        acc0 = __builtin_amdgcn_mfma_f32_32x32x16_bf16(ah1.v, bh01, acc0, 0, 0, 0);    \
        acc1 = __builtin_amdgcn_mfma_f32_32x32x16_bf16(ah1.v, bh11, acc1, 0, 0, 0);    \
        acc0 = __builtin_amdgcn_mfma_f32_32x32x16_bf16(ah1.v, bl01, acc0, 0, 0, 0);    \
        acc1 = __builtin_amdgcn_mfma_f32_32x32x16_bf16(ah1.v, bl11, acc1, 0, 0, 0);    \
        acc0 = __builtin_amdgcn_mfma_f32_32x32x16_bf16(al1.v, bh01, acc0, 0, 0, 0);    \
        acc1 = __builtin_amdgcn_mfma_f32_32x32x16_bf16(al1.v, bh11, acc1, 0, 0, 0);    \
    } while (0)

    // prologue: stage tile 0
    STAGE_X(0, 0);
    LOAD_W(0);
    WRITE_W(0);
    __syncthreads();

    int cur = 0;
    for (int t32 = 0; t32 < 31; ++t32) {
        const int k0n = (t32 + 1) * BK;
        STAGE_X(cur ^ 1, k0n);   // async x -> LDS (next)
        LOAD_W(k0n);             // W -> regs (next)
        COMPUTE(cur);
        WRITE_W(cur ^ 1);        // regs -> LDS (next)
        __syncthreads();         // drains vmcnt+lgkm: next tile ready
        cur ^= 1;
    }
    COMPUTE(cur);

    // In-register softmax. D-layout: col = lane&31, row = (r&3) + 8*(r>>2) + 4*hi.
    const size_t orow_base = br + (size_t)w * 32;
    #pragma unroll
    for (int r = 0; r < 16; ++r) {
        const int row = (r & 3) + 8 * (r >> 2) + 4 * hi;
        const float v0 = acc0[r];
        const float v1 = acc1[r];
        float m = fmaxf(v0, v1);
        m = fmaxf(m, __shfl_xor(m, 1));
        m = fmaxf(m, __shfl_xor(m, 2));
        m = fmaxf(m, __shfl_xor(m, 4));
        m = fmaxf(m, __shfl_xor(m, 8));
        m = fmaxf(m, __shfl_xor(m, 16));
        const float e0 = __expf(v0 - m);
        const float e1 = __expf(v1 - m);
        float s = e0 + e1;
        s += __shfl_xor(s, 1);
        s += __shfl_xor(s, 2);
        s += __shfl_xor(s, 4);
        s += __shfl_xor(s, 8);
        s += __shfl_xor(s, 16);
        const float inv = 1.0f / s;
        float* wo = w_out + (orow_base + row) * EEXP;
        wo[cl]      = e0 * inv;
        wo[32 + cl] = e1 * inv;
    }
#undef STAGE_X
#undef LOAD_W
#undef WRITE_W
#undef SPLIT8
#undef COMPUTE
}

__global__ __launch_bounds__(256) void segsum_kernel(
    const float* __restrict__ w,
    const int*   __restrict__ sorted_rows,
    const int*   __restrict__ offsets,
    float*       __restrict__ pen_sum,
    float*       __restrict__ uniq)
{
    const int d  = blockIdx.x;
    const int t  = threadIdx.x;
    const int e  = t & 63;
    const int rg = t >> 6;
    const int start = offsets[d];
    const int end   = offsets[d + 1];
    const int n     = end - start;

    float s1 = 0.0f, s2 = 0.0f;
    for (int i = start + rg; i < end; i += 4) {
        const int row = sorted_rows[i];
        const float v = w[(size_t)row * EEXP + e];
        s1 += v;
        s2 += v * v;
    }

    __shared__ float ls1[4][64], ls2[4][64];
    ls1[rg][e] = s1;
    ls2[rg][e] = s2;
    __syncthreads();

    if (t < 64) {
        const float a = ls1[0][e] + ls1[1][e] + ls1[2][e] + ls1[3][e];
        const float b = ls2[0][e] + ls2[1][e] + ls2[2][e] + ls2[3][e];
        const float safe = fmaxf((float)n, 1.0f);
        float contrib = b - a * a / safe;
        #pragma unroll
        for (int off = 32; off > 0; off >>= 1)
            contrib += __shfl_down(contrib, off);
        if (e == 0) {
            if (n > 1) atomicAdd(pen_sum, contrib / (safe * (float)EEXP));
            if (n > 0) atomicAdd(uniq, 1.0f);
        }
    }
}

__global__ void final_kernel(const float* __restrict__ pen_sum,
                             const float* __restrict__ uniq,
                             float* __restrict__ pen_out) {
    pen_out[0] = pen_sum[0] / uniq[0];
}

extern "C" void kernel_launch(void* const* d_in, const int* in_sizes, int n_in,
                              void* d_out, int out_size, void* d_ws, size_t ws_size,
                              hipStream_t stream) {
    const float* x   = (const float*)d_in[0];
    const int*   idx = (const int*)d_in[1];
    const float* Wg  = (const float*)d_in[2];

    float* out   = (float*)d_out;
    float* w_out = out;                                  // NROWS*EEXP floats
    float* pen   = out + (size_t)NROWS * EEXP;           // 1 float

    ushort_t* Whg = (ushort_t*)d_ws;
    ushort_t* Wlg = Whg + (size_t)EEXP * DDIM;
    int* sorted_rows = (int*)(Wlg + (size_t)EEXP * DDIM);
    int* offsets     = sorted_rows + NROWS;
    int* cnt         = offsets + NDOCS + 1;
    int* cursor      = cnt + NDOCS;
    float* pen_sum   = (float*)(cursor + NDOCS);
    float* uniq      = pen_sum + 1;

    init_kernel<<<1, 1024, 0, stream>>>(cnt, pen_sum, uniq);
    hist_kernel<<<NROWS / 256, 256, 0, stream>>>(idx, cnt);
    scan_kernel<<<1, 1024, 0, stream>>>(cnt, offsets, cursor);
    scatter_kernel<<<NROWS / 256, 256, 0, stream>>>(idx, cursor, sorted_rows);
    convw_kernel<<<(EEXP * DDIM) / 256, 256, 0, stream>>>(Wg, Whg, Wlg);
    gemm_softmax_kernel<<<NROWS / BM, 256, 0, stream>>>(x, Whg, Wlg, w_out);
    segsum_kernel<<<NDOCS, 256, 0, stream>>>(w_out, sorted_rows, offsets, pen_sum, uniq);
    final_kernel<<<1, 1, 0, stream>>>(pen_sum, uniq, pen);
}

// Round 5
// 454.595 us; speedup vs baseline: 4.3893x; 1.0322x over previous
//
#include <hip/hip_runtime.h>
#include <math.h>

#define NROWS 262144
#define DDIM  1024
#define EEXP  64
#define NDOCS 1024
#define BM    128
#define BK    32

typedef __attribute__((ext_vector_type(8)))  __bf16 bf16x8;
typedef __attribute__((ext_vector_type(16))) float  f32x16;
typedef unsigned short ushort_t;
typedef unsigned int   uint_t;

// ws layout:
//   Whg ushort[EEXP*DDIM], Wlg ushort[EEXP*DDIM]
//   sorted_rows int[NROWS], offsets int[NDOCS+1], cnt int[NDOCS], cursor int[NDOCS]
//   pen_sum f32, uniq f32

__global__ __launch_bounds__(1024) void init_kernel(int* cnt, float* pen_sum, float* uniq) {
    const int t = threadIdx.x;
    cnt[t] = 0;
    if (t == 0) { pen_sum[0] = 0.0f; uniq[0] = 0.0f; }
}

__global__ __launch_bounds__(256) void hist_kernel(const int* __restrict__ idx, int* __restrict__ cnt) {
    const int r = blockIdx.x * 256 + threadIdx.x;
    if (r < NROWS) atomicAdd(&cnt[idx[r]], 1);
}

__global__ __launch_bounds__(1024) void scan_kernel(const int* __restrict__ cnt,
                                                    int* __restrict__ offsets,
                                                    int* __restrict__ cursor) {
    __shared__ int sbuf[NDOCS];
    const int t = threadIdx.x;
    const int my = cnt[t];
    sbuf[t] = my;
    __syncthreads();
    for (int off = 1; off < NDOCS; off <<= 1) {
        int add = (t >= off) ? sbuf[t - off] : 0;
        __syncthreads();
        sbuf[t] += add;
        __syncthreads();
    }
    const int excl = sbuf[t] - my;
    offsets[t] = excl;
    cursor[t]  = excl;
    if (t == NDOCS - 1) offsets[NDOCS] = sbuf[t];
}

__global__ __launch_bounds__(256) void scatter_kernel(const int* __restrict__ idx,
                                                      int* __restrict__ cursor,
                                                      int* __restrict__ sorted_rows) {
    const int r = blockIdx.x * 256 + threadIdx.x;
    if (r < NROWS) {
        const int pos = atomicAdd(&cursor[idx[r]], 1);
        sorted_rows[pos] = r;
    }
}

__global__ __launch_bounds__(256) void convw_kernel(const float* __restrict__ Wg,
                                                    ushort_t* __restrict__ Whg,
                                                    ushort_t* __restrict__ Wlg) {
    const int i = blockIdx.x * 256 + threadIdx.x;
    const float wv = Wg[i];
    const uint_t b = __float_as_uint(wv);
    const float lov = wv - __uint_as_float(b & 0xFFFF0000u);
    Whg[i] = (ushort_t)(b >> 16);
    Wlg[i] = (ushort_t)(__float_as_uint(lov) >> 16);
}

__device__ __forceinline__ void gl2lds16(const float* g, float* l) {
    __builtin_amdgcn_global_load_lds(
        (const __attribute__((address_space(1))) void*)g,
        (__attribute__((address_space(3))) void*)l,
        16, 0, 0);
}

#define ASM_VMCNT6() asm volatile("s_waitcnt vmcnt(6)" ::: "memory")
#define ASM_VMCNT4() asm volatile("s_waitcnt vmcnt(4)" ::: "memory")
#define ASM_VMCNT0() asm volatile("s_waitcnt vmcnt(0)" ::: "memory")
#define ASM_LGKM0()  asm volatile("s_waitcnt lgkmcnt(0)" ::: "memory")
#define BARRIER()    __builtin_amdgcn_s_barrier()

// MFMA GEMM: BM=128, BK=32, 4 waves, 32x32x16 bf16 split-hi/lo (3 products).
// Counted-vmcnt pipeline (T4): per iter issue [2 W-loads, 4 x global_load_lds];
// vmcnt(6) -> barrier -> compute(t); vmcnt(4) -> ds_write W(t+1) -> lgkm(0) -> barrier.
// x(t+1) loads stay in flight across both barriers -> continuous HBM feed.
__global__ __launch_bounds__(256) void gemm_softmax_kernel(
    const float*    __restrict__ x,
    const ushort_t* __restrict__ Whg,
    const ushort_t* __restrict__ Wlg,
    float*          __restrict__ w_out)
{
    __shared__ float    xs[2][BM * BK];       // 2 x 16 KB, row stride 32 f32, 16B-unit XOR swizzle (unit ^ row&7)
    __shared__ ushort_t whs[2][EEXP * 40];    // 2 x 5 KB, row stride 40 ushort (80 B)
    __shared__ ushort_t wls[2][EEXP * 40];

    const int t   = threadIdx.x;
    const int w   = t >> 6;
    const int l   = t & 63;
    const int cl  = l & 31;     // A-row-in-wave-tile / B-col / D-col
    const int hi  = l >> 5;     // k-half selector
    const size_t br = (size_t)blockIdx.x * BM;

    // x staging lane coords: wave w owns chunks 4w..4w+3; chunk = 8 rows x 8 units
    const int lrow  = l >> 3;
    const int lunit = l & 7;

    // W staging coords
    const int se  = t >> 2;     // expert 0..63
    const int skq = t & 3;      // 8-ushort chunk

    f32x16 acc0 = {};
    f32x16 acc1 = {};
    uint4 wh_reg, wl_reg;

    union u8b { uint_t u[4]; bf16x8 v; };

#define LOAD_W(k0) do {                                                                \
        wh_reg = *(const uint4*)(Whg + (size_t)se * DDIM + (k0) + skq * 8);            \
        wl_reg = *(const uint4*)(Wlg + (size_t)se * DDIM + (k0) + skq * 8);            \
    } while (0)

#define STAGE_X(buf, k0) do {                                                          \
        _Pragma("unroll")                                                              \
        for (int i_ = 0; i_ < 4; ++i_) {                                               \
            const int chunk_ = w * 4 + i_;                                             \
            const int row_   = chunk_ * 8 + lrow;                                      \
            const float* gp_ = x + (br + row_) * DDIM + (k0) + ((lunit ^ (row_ & 7)) * 4); \
            gl2lds16(gp_, &xs[buf][chunk_ * 256]);                                     \
        } } while (0)

#define WRITE_W(buf) do {                                                              \
        *(uint4*)(whs[buf] + se * 40 + skq * 8) = wh_reg;                              \
        *(uint4*)(wls[buf] + se * 40 + skq * 8) = wl_reg;                              \
    } while (0)

#define SPLIT8(A, B, AH, AL) do {                                                      \
        const float av_[8] = {A.x, A.y, A.z, A.w, B.x, B.y, B.z, B.w};                 \
        _Pragma("unroll")                                                              \
        for (int p_ = 0; p_ < 4; ++p_) {                                               \
            const uint_t b0_ = __float_as_uint(av_[2 * p_]);                           \
            const uint_t b1_ = __float_as_uint(av_[2 * p_ + 1]);                       \
            AH.u[p_] = (b0_ >> 16) | (b1_ & 0xFFFF0000u);                              \
            const float l0_ = av_[2 * p_]     - __uint_as_float(b0_ & 0xFFFF0000u);    \
            const float l1_ = av_[2 * p_ + 1] - __uint_as_float(b1_ & 0xFFFF0000u);    \
            AL.u[p_] = (__float_as_uint(l0_) >> 16) | (__float_as_uint(l1_) & 0xFFFF0000u); \
        } } while (0)

#define COMPUTE(buf) do {                                                              \
        const int arow_ = w * 32 + cl;                                                 \
        const int sw7_  = arow_ & 7;                                                   \
        const float4 a0_ = *(const float4*)&xs[buf][arow_ * 32 + (((2*hi + 0) ^ sw7_) * 4)]; \
        const float4 a1_ = *(const float4*)&xs[buf][arow_ * 32 + (((2*hi + 1) ^ sw7_) * 4)]; \
        const float4 a2_ = *(const float4*)&xs[buf][arow_ * 32 + (((4 + 2*hi + 0) ^ sw7_) * 4)]; \
        const float4 a3_ = *(const float4*)&xs[buf][arow_ * 32 + (((4 + 2*hi + 1) ^ sw7_) * 4)]; \
        u8b ah0, al0, ah1, al1;                                                        \
        SPLIT8(a0_, a1_, ah0, al0);                                                    \
        SPLIT8(a2_, a3_, ah1, al1);                                                    \
        const int ko_ = 8 * hi;                                                        \
        const bf16x8 bh00 = *(const bf16x8*)(whs[buf] + (cl)      * 40 +      ko_);    \
        const bf16x8 bh01 = *(const bf16x8*)(whs[buf] + (cl)      * 40 + 16 + ko_);    \
        const bf16x8 bh10 = *(const bf16x8*)(whs[buf] + (32 + cl) * 40 +      ko_);    \
        const bf16x8 bh11 = *(const bf16x8*)(whs[buf] + (32 + cl) * 40 + 16 + ko_);    \
        const bf16x8 bl00 = *(const bf16x8*)(wls[buf] + (cl)      * 40 +      ko_);    \
        const bf16x8 bl01 = *(const bf16x8*)(wls[buf] + (cl)      * 40 + 16 + ko_);    \
        const bf16x8 bl10 = *(const bf16x8*)(wls[buf] + (32 + cl) * 40 +      ko_);    \
        const bf16x8 bl11 = *(const bf16x8*)(wls[buf] + (32 + cl) * 40 + 16 + ko_);    \
        acc0 = __builtin_amdgcn_mfma_f32_32x32x16_bf16(ah0.v, bh00, acc0, 0, 0, 0);    \
        acc1 = __builtin_amdgcn_mfma_f32_32x32x16_bf16(ah0.v, bh10, acc1, 0, 0, 0);    \
        acc0 = __builtin_amdgcn_mfma_f32_32x32x16_bf16(ah0.v, bl00, acc0, 0, 0, 0);    \
        acc1 = __builtin_amdgcn_mfma_f32_32x32x16_bf16(ah0.v, bl10, acc1, 0, 0, 0);    \
        acc0 = __builtin_amdgcn_mfma_f32_32x32x16_bf16(al0.v, bh00, acc0, 0, 0, 0);    \
        acc1 = __builtin_amdgcn_mfma_f32_32x32x16_bf16(al0.v, bh10, acc1, 0, 0, 0);    \
        acc0 = __builtin_amdgcn_mfma_f32_32x32x16_bf16(ah1.v, bh01, acc0, 0, 0, 0);    \
        acc1 = __builtin_amdgcn_mfma_f32_32x32x16_bf16(ah1.v, bh11, acc1, 0, 0, 0);    \
        acc0 = __builtin_amdgcn_mfma_f32_32x32x16_bf16(ah1.v, bl01, acc0, 0, 0, 0);    \
        acc1 = __builtin_amdgcn_mfma_f32_32x32x16_bf16(ah1.v, bl11, acc1, 0, 0, 0);    \
        acc0 = __builtin_amdgcn_mfma_f32_32x32x16_bf16(al1.v, bh01, acc0, 0, 0, 0);    \
        acc1 = __builtin_amdgcn_mfma_f32_32x32x16_bf16(al1.v, bh11, acc1, 0, 0, 0);    \
    } while (0)

    // prologue: tile 0.  Issue order [2 W, 4 x] -> vmcnt(4) waits W only.
    LOAD_W(0);
    STAGE_X(0, 0);
    ASM_VMCNT4();
    WRITE_W(0);
    ASM_LGKM0();
    BARRIER();

    int cur = 0;
    #pragma unroll 1
    for (int t32 = 0; t32 < 31; ++t32) {
        const int k0n = (t32 + 1) * BK;
        LOAD_W(k0n);               // 2 vm loads (tile t+1)
        STAGE_X(cur ^ 1, k0n);     // 4 gl2lds (tile t+1) -- stay in flight across barriers
        ASM_VMCNT6();              // all pre-iter ops done: x(t) is in LDS
        BARRIER();                 // tile t fully staged for all waves
        COMPUTE(cur);
        ASM_VMCNT4();              // W(t+1) regs landed; x(t+1) still flying
        WRITE_W(cur ^ 1);
        ASM_LGKM0();
        BARRIER();                 // W(t+1) visible; nobody still reading buf cur^1
        cur ^= 1;
    }
    ASM_VMCNT0();                  // final x tile landed
    BARRIER();
    COMPUTE(cur);

    // In-register softmax. D-layout: col = lane&31, row = (r&3) + 8*(r>>2) + 4*hi.
    const size_t orow_base = br + (size_t)w * 32;
    #pragma unroll
    for (int r = 0; r < 16; ++r) {
        const int row = (r & 3) + 8 * (r >> 2) + 4 * hi;
        const float v0 = acc0[r];
        const float v1 = acc1[r];
        float m = fmaxf(v0, v1);
        m = fmaxf(m, __shfl_xor(m, 1));
        m = fmaxf(m, __shfl_xor(m, 2));
        m = fmaxf(m, __shfl_xor(m, 4));
        m = fmaxf(m, __shfl_xor(m, 8));
        m = fmaxf(m, __shfl_xor(m, 16));
        const float e0 = __expf(v0 - m);
        const float e1 = __expf(v1 - m);
        float s = e0 + e1;
        s += __shfl_xor(s, 1);
        s += __shfl_xor(s, 2);
        s += __shfl_xor(s, 4);
        s += __shfl_xor(s, 8);
        s += __shfl_xor(s, 16);
        const float inv = 1.0f / s;
        float* wo = w_out + (orow_base + row) * EEXP;
        wo[cl]      = e0 * inv;
        wo[32 + cl] = e1 * inv;
    }
#undef LOAD_W
#undef STAGE_X
#undef WRITE_W
#undef SPLIT8
#undef COMPUTE
}

// One block per doc. Row list prefetched to LDS to break the load->load chain.
__global__ __launch_bounds__(256) void segsum_kernel(
    const float* __restrict__ w,
    const int*   __restrict__ sorted_rows,
    const int*   __restrict__ offsets,
    float*       __restrict__ pen_sum,
    float*       __restrict__ uniq)
{
    __shared__ int rows_s[512];
    __shared__ float ls1[4][64], ls2[4][64];

    const int d  = blockIdx.x;
    const int t  = threadIdx.x;
    const int e  = t & 63;
    const int rg = t >> 6;
    const int start = offsets[d];
    const int end   = offsets[d + 1];
    const int n     = end - start;

    for (int i = t; i < n && i < 512; i += 256) rows_s[i] = sorted_rows[start + i];
    __syncthreads();

    float s1 = 0.0f, s2 = 0.0f;
    for (int i = rg; i < n; i += 4) {
        const int row = (i < 512) ? rows_s[i] : sorted_rows[start + i];
        const float v = w[(size_t)row * EEXP + e];
        s1 += v;
        s2 += v * v;
    }

    ls1[rg][e] = s1;
    ls2[rg][e] = s2;
    __syncthreads();

    if (t < 64) {
        const float a = ls1[0][e] + ls1[1][e] + ls1[2][e] + ls1[3][e];
        const float b = ls2[0][e] + ls2[1][e] + ls2[2][e] + ls2[3][e];
        const float safe = fmaxf((float)n, 1.0f);
        float contrib = b - a * a / safe;
        #pragma unroll
        for (int off = 32; off > 0; off >>= 1)
            contrib += __shfl_down(contrib, off);
        if (e == 0) {
            if (n > 1) atomicAdd(pen_sum, contrib / (safe * (float)EEXP));
            if (n > 0) atomicAdd(uniq, 1.0f);
        }
    }
}

__global__ void final_kernel(const float* __restrict__ pen_sum,
                             const float* __restrict__ uniq,
                             float* __restrict__ pen_out) {
    pen_out[0] = pen_sum[0] / uniq[0];
}

extern "C" void kernel_launch(void* const* d_in, const int* in_sizes, int n_in,
                              void* d_out, int out_size, void* d_ws, size_t ws_size,
                              hipStream_t stream) {
    const float* x   = (const float*)d_in[0];
    const int*   idx = (const int*)d_in[1];
    const float* Wg  = (const float*)d_in[2];

    float* out   = (float*)d_out;
    float* w_out = out;                                  // NROWS*EEXP floats
    float* pen   = out + (size_t)NROWS * EEXP;           // 1 float

    ushort_t* Whg = (ushort_t*)d_ws;
    ushort_t* Wlg = Whg + (size_t)EEXP * DDIM;
    int* sorted_rows = (int*)(Wlg + (size_t)EEXP * DDIM);
    int* offsets     = sorted_rows + NROWS;
    int* cnt         = offsets + NDOCS + 1;
    int* cursor      = cnt + NDOCS;
    float* pen_sum   = (float*)(cursor + NDOCS);
    float* uniq      = pen_sum + 1;

    init_kernel<<<1, 1024, 0, stream>>>(cnt, pen_sum, uniq);
    hist_kernel<<<NROWS / 256, 256, 0, stream>>>(idx, cnt);
    scan_kernel<<<1, 1024, 0, stream>>>(cnt, offsets, cursor);
    scatter_kernel<<<NROWS / 256, 256, 0, stream>>>(idx, cursor, sorted_rows);
    convw_kernel<<<(EEXP * DDIM) / 256, 256, 0, stream>>>(Wg, Whg, Wlg);
    gemm_softmax_kernel<<<NROWS / BM, 256, 0, stream>>>(x, Whg, Wlg, w_out);
    segsum_kernel<<<NDOCS, 256, 0, stream>>>(w_out, sorted_rows, offsets, pen_sum, uniq);
    final_kernel<<<1, 1, 0, stream>>>(pen_sum, uniq, pen);
}